// Round 1
// baseline (510.312 us; speedup 1.0000x reference)
//
#include <hip/hip_runtime.h>

#define N_NODES  200000
#define N_CHILD  32
#define N_LAYERS 8

// One thread per node. Child indices for a node are contiguous (node*32),
// loaded as 8x int4. Gathers from vals_in are random 4B reads into an 800KB
// table -> L2-resident on every XCD.
__global__ __launch_bounds__(256) void layer_kernel(
    const float* __restrict__ vals_in,
    float*       __restrict__ vals_out,
    const int*   __restrict__ child_idx,   // [N_NODES][N_CHILD] for this layer
    const int*   __restrict__ fun_ids,     // [N_NODES] for this layer
    const float* __restrict__ wptr)
{
    int node = blockIdx.x * blockDim.x + threadIdx.x;
    if (node >= N_NODES) return;

    const int4* ci = (const int4*)(child_idx + (size_t)node * N_CHILD);
    float s = 0.0f;
#pragma unroll
    for (int j = 0; j < N_CHILD / 4; ++j) {
        int4 c = ci[j];
        s += vals_in[c.x] + vals_in[c.y] + vals_in[c.z] + vals_in[c.w];
    }

    float x = wptr[0] * s;
    int fid = fun_ids[node];
    float y;
    if (fid == 0) {
        y = tanhf(x);
    } else if (fid == 1) {
        // sigmoid; overflow-safe: exp(-x)->inf => y->0, exp(-x)->0 => y->1
        y = 1.0f / (1.0f + __expf(-x));
    } else if (fid == 2) {
        y = fmaxf(x, 0.0f);
    } else {
        y = x;
    }
    vals_out[node] = y;
}

extern "C" void kernel_launch(void* const* d_in, const int* in_sizes, int n_in,
                              void* d_out, int out_size, void* d_ws, size_t ws_size,
                              hipStream_t stream) {
    const float* X         = (const float*)d_in[0];
    const float* w         = (const float*)d_in[1];
    const int*   child_idx = (const int*)d_in[2];
    const int*   fun_ids   = (const int*)d_in[3];
    float*       out       = (float*)d_out;
    float*       bufA      = (float*)d_ws;   // 800 KB ping buffer

    const int threads = 256;
    const int blocks  = (N_NODES + threads - 1) / threads;

    const float* cur = X;
    for (int l = 0; l < N_LAYERS; ++l) {
        // even layers -> bufA, odd layers -> d_out; layer 7 (last) -> d_out
        float* nxt = (l & 1) ? out : bufA;
        layer_kernel<<<blocks, threads, 0, stream>>>(
            cur, nxt,
            child_idx + (size_t)l * N_NODES * N_CHILD,
            fun_ids   + (size_t)l * N_NODES,
            w);
        cur = nxt;
    }
}